// Round 4
// baseline (218.325 us; speedup 1.0000x reference)
//
#include <hip/hip_runtime.h>
#include <hip/hip_bf16.h>

#define B_N 32
#define C_K 512
#define T_N 1024
#define D_M 512

constexpr int BM = 128, BN = 128, BK = 32;
constexpr int SA = 40;           // shorts per LDS row: 80B rows, 16B-aligned, 20-bank stride
constexpr int KSTEPS = C_K / BK; // 16

typedef __attribute__((ext_vector_type(4))) float floatx4;
typedef __attribute__((ext_vector_type(8))) short shortx8;
typedef __attribute__((ext_vector_type(4))) unsigned int uintx4;

__device__ __forceinline__ unsigned pk2(float a, float b) {
  __hip_bfloat162 h = __float22bfloat162_rn(make_float2(a, b));
  union { __hip_bfloat162 v; unsigned u; } c; c.v = h; return c.u;
}

// Barrier that does NOT drain vmcnt: LDS ops fenced via lgkmcnt(0), global
// loads stay in flight across the barrier (dodges the m97 vmcnt(0) drain).
__device__ __forceinline__ void lds_barrier() {
  asm volatile("s_waitcnt lgkmcnt(0)\n\ts_barrier" ::: "memory");
}

// cvt fp32x4-of-8-rows -> 4 rows of 8 bf16, one ds_write_b128 per row
__device__ __forceinline__ void stage(const floatx4* v, short* dst) {
  #pragma unroll
  for (int r = 0; r < 4; ++r) {
    uintx4 pkv = { pk2(v[0][r], v[1][r]), pk2(v[2][r], v[3][r]),
                   pk2(v[4][r], v[5][r]), pk2(v[6][r], v[7][r]) };
    *(uintx4*)(dst + r * SA) = pkv;
  }
}

__device__ __forceinline__ void mfma_step(const short* pa, const short* pb,
                                          floatx4 (&acc)[4][4]) {
  shortx8 af[4], bg[4];
  #pragma unroll
  for (int i = 0; i < 4; ++i) {
    af[i] = *(const shortx8*)(pa + 16 * i * SA); // ds_read_b128, conflict-free
    bg[i] = *(const shortx8*)(pb + 16 * i * SA);
  }
  #pragma unroll
  for (int i = 0; i < 4; ++i)
    #pragma unroll
    for (int j = 0; j < 4; ++j)
      acc[i][j] = __builtin_amdgcn_mfma_f32_16x16x32_bf16(af[i], bg[j], acc[i][j], 0, 0, 0);
}

// out[b,d,t] = sum_c x[b,c,t] * W[sub[b],c,d] + bias[sub[b],d]
__global__ __launch_bounds__(256, 3)
void subject_gemm(const float* __restrict__ x, const int* __restrict__ subjects,
                  const float* __restrict__ weights, const float* __restrict__ bias,
                  float* __restrict__ out)
{
  __shared__ short lds_a[2][BM * SA]; // [m][k] bf16
  __shared__ short lds_b[2][BN * SA]; // [n][k]

  // XCD swizzle: all 32 tiles of a batch on one XCD (FETCH 148->81MB in R3)
  const int bid  = blockIdx.x;
  const int xcd  = bid & 7;
  const int s    = bid >> 3;
  const int b    = xcd * 4 + (s & 3);
  const int tile = s >> 2;
  const int tm = tile >> 3, tn = tile & 7;
  const int m0 = tm * BM, n0 = tn * BN;
  const int nb = subjects[b];

  const float* __restrict__ Wp = weights + (size_t)nb * C_K * D_M; // [k][m]
  const float* __restrict__ Xp = x + (size_t)b * C_K * T_N;        // [k][n]

  const int tid  = threadIdx.x;
  const int lane = tid & 63;
  const int wave = tid >> 6;

  // staging role: waves 0-1 stage A, waves 2-3 stage B
  // oct = lane&3 (k-octet), mgg = lane>>2 (column group) -> conflict-free b128 writes
  const bool isA = (wave < 2);
  const int  mgg = (wave & 1) * 16 + (lane >> 2); // 4 columns at 4*mgg
  const int  oct = lane & 3;                      // k = 8*oct + jj
  const float* gsrc = isA ? (Wp + (size_t)(8 * oct) * D_M + (m0 + 4 * mgg))
                          : (Xp + (size_t)(8 * oct) * T_N + (n0 + 4 * mgg));
  const int gs = isA ? D_M : T_N;
  short* const wb0 = (isA ? lds_a[0] : lds_b[0]) + (4 * mgg) * SA + 8 * oct;
  short* const wb1 = (isA ? lds_a[1] : lds_b[1]) + (4 * mgg) * SA + 8 * oct;
  const size_t gstep = (size_t)BK * gs;

  // compute role: 64x64 wave tile
  const int wm = (wave & 1) * 64, wn = (wave >> 1) * 64;
  const int l15 = lane & 15, q = lane >> 4;
  const short* pa0 = lds_a[0] + (wm + l15) * SA + 8 * q;
  const short* pb0 = lds_b[0] + (wn + l15) * SA + 8 * q;
  const short* pa1 = lds_a[1] + (wm + l15) * SA + 8 * q;
  const short* pb1 = lds_b[1] + (wn + l15) * SA + 8 * q;

  floatx4 acc[4][4] = {};
  floatx4 u[8], w[8];

  // prologue: tile0 -> u -> buf0; tile1 -> w (in flight)
  #pragma unroll
  for (int jj = 0; jj < 8; ++jj) u[jj] = *(const floatx4*)(gsrc + (size_t)jj * gs);
  stage(u, wb0);
  #pragma unroll
  for (int jj = 0; jj < 8; ++jj) w[jj] = *(const floatx4*)(gsrc + gstep + (size_t)jj * gs);
  const float* gnext = gsrc + 2 * gstep;

  for (int ks = 0; ks < KSTEPS; ks += 2) {
    // even: compute buf0 (tile ks); load tile ks+2 -> u; stage w (tile ks+1) -> buf1
    lds_barrier();
    if (ks + 2 < KSTEPS) {
      #pragma unroll
      for (int jj = 0; jj < 8; ++jj) u[jj] = *(const floatx4*)(gnext + (size_t)jj * gs);
      gnext += gstep;
    }
    mfma_step(pa0, pb0, acc);
    stage(w, wb1); // vmcnt wait for w's loads lands here, ~1.5 ksteps after issue

    // odd: compute buf1 (tile ks+1); load tile ks+3 -> w; stage u (tile ks+2) -> buf0
    lds_barrier();
    if (ks + 3 < KSTEPS) {
      #pragma unroll
      for (int jj = 0; jj < 8; ++jj) w[jj] = *(const floatx4*)(gnext + (size_t)jj * gs);
      gnext += gstep;
    }
    mfma_step(pa1, pb1, acc);
    if (ks + 2 < KSTEPS) stage(u, wb0);
  }

  // epilogue: C/D layout col = lane&15 (t), row = 4*(lane>>4) + reg (d)
  float* __restrict__ O = out + (size_t)b * D_M * T_N;
  const float* __restrict__ bb = bias + (size_t)nb * D_M;
  #pragma unroll
  for (int i = 0; i < 4; ++i) {
    const floatx4 bv = *(const floatx4*)(bb + m0 + wm + 16 * i + 4 * q);
    #pragma unroll
    for (int r = 0; r < 4; ++r) {
      const int d = m0 + wm + 16 * i + 4 * q + r;
      #pragma unroll
      for (int j = 0; j < 4; ++j) {
        const int t = n0 + wn + 16 * j + l15;
        O[(size_t)d * T_N + t] = acc[i][j][r] + bv[r];
      }
    }
  }
}

extern "C" void kernel_launch(void* const* d_in, const int* in_sizes, int n_in,
                              void* d_out, int out_size, void* d_ws, size_t ws_size,
                              hipStream_t stream) {
  const float* x        = (const float*)d_in[0];
  const int*   subjects = (const int*)d_in[1];
  const float* weights  = (const float*)d_in[2];
  const float* bias     = (const float*)d_in[3];
  float* out = (float*)d_out;
  (void)in_sizes; (void)n_in; (void)out_size; (void)d_ws; (void)ws_size;

  dim3 grid(B_N * 4 * 8); // 1024 blocks: 32 b x 4 tm x 8 tn
  dim3 block(256);
  hipLaunchKernelGGL(subject_gemm, grid, block, 0, stream, x, subjects, weights, bias, out);
}